// Round 13
// baseline (108.209 us; speedup 1.0000x reference)
//
#include <hip/hip_runtime.h>

typedef unsigned short u16;
typedef float  f32x4  __attribute__((ext_vector_type(4)));
typedef int    i32x4  __attribute__((ext_vector_type(4)));
typedef __bf16 bf16x8 __attribute__((ext_vector_type(8)));

// Problem constants
constexpr int B_ = 8, T_ = 128, U_ = 64, D_ = 512, V_ = 1024;
constexpr int M_ = B_ * T_ * U_;   // 65536

// ---------------------------------------------------------------------------
// prep_w: W (V,D) f32 -> bf16 in MFMA-fragment order (validated R8):
//   Wb2[((vg*16 + kc)*64 + ko*16 + vc)*8 + ke],  v=vg*16+vc, k=kc*32+ko*8+ke.
// One 16x16x32 B-fragment = 64 lanes x 16B = one coalesced dwordx4.
// Block 0 also writes the lengths pass-through (as f32 values).
// ---------------------------------------------------------------------------
__global__ void prep_w(const float* __restrict__ W,
                       const int* __restrict__ sl, const int* __restrict__ tl,
                       u16* __restrict__ Wb2, float* __restrict__ tail) {
  if (blockIdx.x == 0 && threadIdx.x < 16) {
    const int t = threadIdx.x;
    tail[t] = (t < 8) ? (float)sl[t] : (float)tl[t - 8];
  }
  const int tid = blockIdx.x * 256 + threadIdx.x;   // 65536 threads
  const int v  = tid >> 6;        // 0..1023
  const int cs = tid & 63;        // 8-elem chunk, k = cs*8
  const float* sp = W + (size_t)v * D_ + cs * 8;
  float4 w0 = *(const float4*)sp;
  float4 w1 = *(const float4*)(sp + 4);
  union { __bf16 h[8]; i32x4 x; } pk;
  pk.h[0] = (__bf16)w0.x; pk.h[1] = (__bf16)w0.y;
  pk.h[2] = (__bf16)w0.z; pk.h[3] = (__bf16)w0.w;
  pk.h[4] = (__bf16)w1.x; pk.h[5] = (__bf16)w1.y;
  pk.h[6] = (__bf16)w1.z; pk.h[7] = (__bf16)w1.w;
  const int vg = v >> 4, vc = v & 15;
  const int kc = cs >> 2, ko = cs & 3;
  *(i32x4*)(Wb2 + (((size_t)(vg * 16 + kc) * 64 + ko * 16 + vc) * 8)) = pk.x;
}

__global__ void tail_k(const int* __restrict__ sl, const int* __restrict__ tl,
                       float* __restrict__ tail) {
  const int t = threadIdx.x;
  if (t < 8)       tail[t] = (float)sl[t];
  else if (t < 16) tail[t] = (float)tl[t - 8];
}

// ---------------------------------------------------------------------------
// Fused joiner GEMM — R10 structure, register-trimmed for 4 blocks/CU.
// BM=BN=128, BK=64, 256 thr (4 waves 2x2), wave tile 64x64.
//  - B fragments: per-k-step coalesced dwordx4 from fragment-ordered Wb2
//    (L2-resident) -> 16 transient VGPR (was 32 held).
//    FIXED vs R12: kc stride is 512 u16 ELEMENTS (was 512*8 -> read garbage).
//  - A: f32 loads INLINE in expand (no held prefetch regs; at 16 waves/CU
//    the TLP hides the load latency that prefetch regs used to hide).
//  - A double-buffered LDS (2x16KB); ONE raw s_barrier per K-tile; only
//    lgkmcnt(0) for ds_write visibility (no vmcnt drains; no gload_lds).
//  - launch_bounds(256,4): VGPR<=128 -> 4 blocks/CU = 16 waves (was 12).
// ---------------------------------------------------------------------------
__global__ __launch_bounds__(256, 4) void joiner_gemm(
    const float* __restrict__ src, const float* __restrict__ tgt,
    const u16* __restrict__ Wb2, const float* __restrict__ bias,
    float* __restrict__ out)
{
  __shared__ __align__(16) char As[2][16384];   // 128 rows x 64 bf16, dbuf

  const int tid  = threadIdx.x;
  const int lane = tid & 63;
  const int wid  = tid >> 6;
  const int bn   = blockIdx.x & 7;   // 8 N-tiles (round-robin: 1 bn per XCD)
  const int bm   = blockIdx.x >> 3;  // 512 M-tiles
  const int bt0  = bm * 2;           // two (b,t) rows per M-tile (U=64)
  const int bb   = bt0 >> 7;         // batch
  const int sr0  = tid >> 3;         // staging row 0..31
  const int sc8  = tid & 7;          // staging 16B chunk 0..7
  const int wm   = (wid >> 1) * 64;
  const int wn   = (wid & 1) * 64;

  f32x4 acc[4][4] = {};

  const float* srcp0 = src + (size_t)bt0 * D_ + sc8 * 8;
  const float* srcp1 = srcp0 + D_;
  const float* tgtp0 = tgt + ((size_t)bb * U_ + sr0) * D_ + sc8 * 8;
  const float* tgtp1 = tgtp0 + (size_t)32 * D_;

  float bv[4];
  #pragma unroll
  for (int ni = 0; ni < 4; ++ni)
    bv[ni] = bias[bn * 128 + wn + ni * 16 + (lane & 15)];

  // B fragment base for ni=0: vg0 = bn*8 + wn/16. Strides (u16 elements):
  //   ni  -> +ni * 8192   (one vg = 16 frags * 512 elems)
  //   kc  -> +kc * 512    (one frag = 64 lanes * 8 elems)
  const u16* bbase = Wb2 + ((size_t)(bn * 8 + (wn >> 4)) * 16 * 64 + lane) * 8;

  auto expandA = [&](int kt, int nb) {  // inline loads + relu/cvt + ds_write
    const int k0 = kt * 64;
    const float4 s0a = *(const float4*)(srcp0 + k0);
    const float4 s0b = *(const float4*)(srcp0 + k0 + 4);
    const float4 s1a = *(const float4*)(srcp1 + k0);
    const float4 s1b = *(const float4*)(srcp1 + k0 + 4);
    const float4 t0a = *(const float4*)(tgtp0 + k0);
    const float4 t0b = *(const float4*)(tgtp0 + k0 + 4);
    const float4 t1a = *(const float4*)(tgtp1 + k0);
    const float4 t1b = *(const float4*)(tgtp1 + k0 + 4);
    #pragma unroll
    for (int i = 0; i < 2; ++i) {
      const float4 sa = i ? s1a : s0a;
      const float4 sb = i ? s1b : s0b;
      #pragma unroll
      for (int j = 0; j < 2; ++j) {
        const float4 ta = j ? t1a : t0a;
        const float4 tb = j ? t1b : t0b;
        const int r = i * 64 + j * 32 + sr0;
        union { __bf16 h[8]; i32x4 x; } pk;
        pk.h[0] = (__bf16)fmaxf(sa.x + ta.x, 0.f);
        pk.h[1] = (__bf16)fmaxf(sa.y + ta.y, 0.f);
        pk.h[2] = (__bf16)fmaxf(sa.z + ta.z, 0.f);
        pk.h[3] = (__bf16)fmaxf(sa.w + ta.w, 0.f);
        pk.h[4] = (__bf16)fmaxf(sb.x + tb.x, 0.f);
        pk.h[5] = (__bf16)fmaxf(sb.y + tb.y, 0.f);
        pk.h[6] = (__bf16)fmaxf(sb.z + tb.z, 0.f);
        pk.h[7] = (__bf16)fmaxf(sb.w + tb.w, 0.f);
        *(i32x4*)(As[nb] + r * 128 + ((sc8 ^ (r & 7)) << 4)) = pk.x;
      }
    }
  };

  auto compute = [&](int kt, int cb) {
    #pragma unroll
    for (int s = 0; s < 2; ++s) {
      // B frags for this k-step: 4 coalesced dwordx4, transient regs
      bf16x8 bgs[4];
      #pragma unroll
      for (int ni = 0; ni < 4; ++ni)
        bgs[ni] = *(const bf16x8*)(bbase + (size_t)ni * 8192
                                         + (size_t)(kt * 2 + s) * 512);
      const int kc = s * 4 + (lane >> 4);
      bf16x8 af[4];
      #pragma unroll
      for (int mi = 0; mi < 4; ++mi) {
        const int r = wm + mi * 16 + (lane & 15);
        af[mi] = *(const bf16x8*)(As[cb] + r * 128 + ((kc ^ (r & 7)) << 4));
      }
      #pragma unroll
      for (int mi = 0; mi < 4; ++mi)
        #pragma unroll
        for (int ni = 0; ni < 4; ++ni)
          acc[mi][ni] = __builtin_amdgcn_mfma_f32_16x16x32_bf16(
              af[mi], bgs[ni], acc[mi][ni], 0, 0, 0);
    }
  };

  // ---- prologue: tile 0 into buf 0 ----
  expandA(0, 0);
  asm volatile("s_waitcnt lgkmcnt(0)" ::: "memory");
  __builtin_amdgcn_sched_barrier(0);
  __builtin_amdgcn_s_barrier();
  __builtin_amdgcn_sched_barrier(0);

  // ---- K-loop: ONE barrier per tile ----
  // Race-free: expand(t+2) runs after bar(t+1), which is after all waves'
  // compute(t) on the same buffer.
  for (int kt = 0; kt < 8; ++kt) {
    compute(kt, kt & 1);
    if (kt < 7) {
      __builtin_amdgcn_sched_barrier(0);
      expandA(kt + 1, (kt + 1) & 1);         // other buffer; overlaps other
                                             // waves' MFMA on this SIMD
      asm volatile("s_waitcnt lgkmcnt(0)" ::: "memory");
      __builtin_amdgcn_sched_barrier(0);
      __builtin_amdgcn_s_barrier();
      __builtin_amdgcn_sched_barrier(0);
    }
  }

  // ---- epilogue: C/D layout col=lane&15, row=(lane>>4)*4+reg ----
  const int col = lane & 15;
  const int r4  = (lane >> 4) * 4;
  #pragma unroll
  for (int mi = 0; mi < 4; ++mi) {
    const size_t mrow = (size_t)bm * 128 + wm + mi * 16 + r4;
    float* op0 = out + mrow * V_ + bn * 128 + wn + col;
    #pragma unroll
    for (int ni = 0; ni < 4; ++ni) {
      float* op = op0 + ni * 16;
      const f32x4 v = acc[mi][ni];
      op[0 * V_] = v[0] + bv[ni];
      op[1 * V_] = v[1] + bv[ni];
      op[2 * V_] = v[2] + bv[ni];
      op[3 * V_] = v[3] + bv[ni];
    }
  }
}

// ---------------------------------------------------------------------------
// Fallback (ws too small): round-1 fused kernel, f32 W in-loop.
// ---------------------------------------------------------------------------
__global__ __launch_bounds__(256, 2) void joiner_gemm_f32(
    const float* __restrict__ src, const float* __restrict__ tgt,
    const float* __restrict__ Wf, const float* __restrict__ bias,
    float* __restrict__ out)
{
  __shared__ char As[128 * 128];
  __shared__ char Bs[128 * 128];

  const int tid  = threadIdx.x;
  const int lane = tid & 63;
  const int wid  = tid >> 6;
  const int bn   = blockIdx.x & 7;
  const int bm   = blockIdx.x >> 3;
  const int bt0  = bm * 2;
  const int bb   = bt0 >> 7;
  const int sr0  = tid >> 3;
  const int sc8  = tid & 7;
  const int wm   = (wid >> 1) * 64;
  const int wn   = (wid & 1) * 64;

  f32x4 acc[4][4] = {};

  const float* srcp0 = src + (size_t)bt0 * D_ + sc8 * 8;
  const float* srcp1 = srcp0 + D_;
  const float* tgtp0 = tgt + ((size_t)bb * U_ + sr0) * D_ + sc8 * 8;
  const float* tgtp1 = tgtp0 + (size_t)32 * D_;

  for (int kt = 0; kt < 8; ++kt) {
    const int k0 = kt * 64;
    #pragma unroll
    for (int jj = 0; jj < 4; ++jj) {
      const int vr = sr0 + 32 * jj;
      const float* wp = Wf + (size_t)(bn * 128 + vr) * D_ + k0 + sc8 * 8;
      float4 w0 = *(const float4*)wp;
      float4 w1 = *(const float4*)(wp + 4);
      union { __bf16 h[8]; i32x4 x; } pk;
      pk.h[0] = (__bf16)w0.x; pk.h[1] = (__bf16)w0.y;
      pk.h[2] = (__bf16)w0.z; pk.h[3] = (__bf16)w0.w;
      pk.h[4] = (__bf16)w1.x; pk.h[5] = (__bf16)w1.y;
      pk.h[6] = (__bf16)w1.z; pk.h[7] = (__bf16)w1.w;
      *(i32x4*)(Bs + vr * 128 + ((sc8 ^ (vr & 7)) << 4)) = pk.x;
    }
    float4 s0a = *(const float4*)(srcp0 + k0), s0b = *(const float4*)(srcp0 + k0 + 4);
    float4 s1a = *(const float4*)(srcp1 + k0), s1b = *(const float4*)(srcp1 + k0 + 4);
    float4 t0a = *(const float4*)(tgtp0 + k0), t0b = *(const float4*)(tgtp0 + k0 + 4);
    float4 t1a = *(const float4*)(tgtp1 + k0), t1b = *(const float4*)(tgtp1 + k0 + 4);
    #pragma unroll
    for (int i = 0; i < 2; ++i) {
      const float4 sa = i ? s1a : s0a;
      const float4 sb = i ? s1b : s0b;
      #pragma unroll
      for (int jj = 0; jj < 2; ++jj) {
        const float4 ta = jj ? t1a : t0a;
        const float4 tb = jj ? t1b : t0b;
        const int r = i * 64 + jj * 32 + sr0;
        union { __bf16 h[8]; i32x4 x; } pk;
        pk.h[0] = (__bf16)fmaxf(sa.x + ta.x, 0.f);
        pk.h[1] = (__bf16)fmaxf(sa.y + ta.y, 0.f);
        pk.h[2] = (__bf16)fmaxf(sa.z + ta.z, 0.f);
        pk.h[3] = (__bf16)fmaxf(sa.w + ta.w, 0.f);
        pk.h[4] = (__bf16)fmaxf(sb.x + tb.x, 0.f);
        pk.h[5] = (__bf16)fmaxf(sb.y + tb.y, 0.f);
        pk.h[6] = (__bf16)fmaxf(sb.z + tb.z, 0.f);
        pk.h[7] = (__bf16)fmaxf(sb.w + tb.w, 0.f);
        *(i32x4*)(As + r * 128 + ((sc8 ^ (r & 7)) << 4)) = pk.x;
      }
    }
    __syncthreads();
    #pragma unroll
    for (int s = 0; s < 2; ++s) {
      const int kc = s * 4 + (lane >> 4);
      bf16x8 af[4], bg[4];
      #pragma unroll
      for (int mi = 0; mi < 4; ++mi) {
        const int r = wm + mi * 16 + (lane & 15);
        af[mi] = *(const bf16x8*)(As + r * 128 + ((kc ^ (r & 7)) << 4));
      }
      #pragma unroll
      for (int ni = 0; ni < 4; ++ni) {
        const int n = wn + ni * 16 + (lane & 15);
        bg[ni] = *(const bf16x8*)(Bs + n * 128 + ((kc ^ (n & 7)) << 4));
      }
      #pragma unroll
      for (int mi = 0; mi < 4; ++mi)
        #pragma unroll
        for (int ni = 0; ni < 4; ++ni)
          acc[mi][ni] = __builtin_amdgcn_mfma_f32_16x16x32_bf16(
              af[mi], bg[ni], acc[mi][ni], 0, 0, 0);
    }
    __syncthreads();
  }

  const int col = lane & 15;
  const int r4  = (lane >> 4) * 4;
  float bv[4];
  #pragma unroll
  for (int ni = 0; ni < 4; ++ni) bv[ni] = bias[bn * 128 + wn + ni * 16 + col];
  #pragma unroll
  for (int mi = 0; mi < 4; ++mi) {
    const size_t mrow = (size_t)bm * 128 + wm + mi * 16 + r4;
    float* op0 = out + mrow * V_ + bn * 128 + wn + col;
    #pragma unroll
    for (int ni = 0; ni < 4; ++ni) {
      float* op = op0 + ni * 16;
      const f32x4 v = acc[mi][ni];
      op[0 * V_] = v[0] + bv[ni];
      op[1 * V_] = v[1] + bv[ni];
      op[2 * V_] = v[2] + bv[ni];
      op[3 * V_] = v[3] + bv[ni];
    }
  }
}

extern "C" void kernel_launch(void* const* d_in, const int* in_sizes, int n_in,
                              void* d_out, int out_size, void* d_ws, size_t ws_size,
                              hipStream_t stream) {
  const float* src  = (const float*)d_in[0];
  const int*   sl   = (const int*)d_in[1];
  const float* tgt  = (const float*)d_in[2];
  const int*   tl   = (const int*)d_in[3];
  const float* W    = (const float*)d_in[4];
  const float* bias = (const float*)d_in[5];
  float* out  = (float*)d_out;
  float* tail = out + (size_t)M_ * V_;

  if (ws_size >= (size_t)V_ * D_ * sizeof(u16)) {
    u16* Wb2 = (u16*)d_ws;
    prep_w<<<256, 256, 0, stream>>>(W, sl, tl, Wb2, tail);
    joiner_gemm<<<(M_ / 128) * (V_ / 128), 256, 0, stream>>>(
        src, tgt, Wb2, bias, out);
  } else {
    tail_k<<<1, 64, 0, stream>>>(sl, tl, tail);
    joiner_gemm_f32<<<(M_ / 128) * (V_ / 128), 256, 0, stream>>>(
        src, tgt, W, bias, out);
  }
}

// Round 14
// 102.233 us; speedup vs baseline: 1.0585x; 1.0585x over previous
//
#include <hip/hip_runtime.h>

typedef unsigned short u16;
typedef float  f32x4  __attribute__((ext_vector_type(4)));
typedef int    i32x4  __attribute__((ext_vector_type(4)));
typedef __bf16 bf16x8 __attribute__((ext_vector_type(8)));

// Problem constants
constexpr int B_ = 8, T_ = 128, U_ = 64, D_ = 512, V_ = 1024;
constexpr int M_ = B_ * T_ * U_;   // 65536

// ---------------------------------------------------------------------------
// prep_w: W (V,D) f32 -> bf16 in MFMA-fragment order (validated R8):
//   Wb2[((vg*16 + kc)*64 + ko*16 + vc)*8 + ke],  v=vg*16+vc, k=kc*32+ko*8+ke.
// One 16x16x32 B-fragment = 64 lanes x 16B = one coalesced dwordx4.
// Block 0 also writes the lengths pass-through (as f32 values).
// ---------------------------------------------------------------------------
__global__ void prep_w(const float* __restrict__ W,
                       const int* __restrict__ sl, const int* __restrict__ tl,
                       u16* __restrict__ Wb2, float* __restrict__ tail) {
  if (blockIdx.x == 0 && threadIdx.x < 16) {
    const int t = threadIdx.x;
    tail[t] = (t < 8) ? (float)sl[t] : (float)tl[t - 8];
  }
  const int tid = blockIdx.x * 256 + threadIdx.x;   // 65536 threads
  const int v  = tid >> 6;        // 0..1023
  const int cs = tid & 63;        // 8-elem chunk, k = cs*8
  const float* sp = W + (size_t)v * D_ + cs * 8;
  float4 w0 = *(const float4*)sp;
  float4 w1 = *(const float4*)(sp + 4);
  union { __bf16 h[8]; i32x4 x; } pk;
  pk.h[0] = (__bf16)w0.x; pk.h[1] = (__bf16)w0.y;
  pk.h[2] = (__bf16)w0.z; pk.h[3] = (__bf16)w0.w;
  pk.h[4] = (__bf16)w1.x; pk.h[5] = (__bf16)w1.y;
  pk.h[6] = (__bf16)w1.z; pk.h[7] = (__bf16)w1.w;
  const int vg = v >> 4, vc = v & 15;
  const int kc = cs >> 2, ko = cs & 3;
  *(i32x4*)(Wb2 + (((size_t)(vg * 16 + kc) * 64 + ko * 16 + vc) * 8)) = pk.x;
}

__global__ void tail_k(const int* __restrict__ sl, const int* __restrict__ tl,
                       float* __restrict__ tail) {
  const int t = threadIdx.x;
  if (t < 8)       tail[t] = (float)sl[t];
  else if (t < 16) tail[t] = (float)tl[t - 8];
}

// ---------------------------------------------------------------------------
// Fused joiner GEMM — champion structure (R10, 103.0 us) + bias-in-acc-init.
// BM=BN=128, BK=64, 256 thr (4 waves 2x2), wave tile 64x64.
//  - B fragments: coalesced dwordx4 from fragment-ordered Wb2 (L2-resident)
//    into 32 held VGPRs. No LDS, no DMA for B.
//  - A: f32 loads -> relu/cvt -> swizzled ds_write, double-buffered (2x16KB);
//    expand(kt+1) overlaps other waves' compute(kt) on the separate VALU pipe.
//  - ONE raw s_barrier per K-tile; no vmcnt drains anywhere (no gload_lds);
//    only lgkmcnt(0) for ds_write visibility.
//  - bias folded into accumulator init (epilogue is pure stores).
// ---------------------------------------------------------------------------
__global__ __launch_bounds__(256, 3) void joiner_gemm(
    const float* __restrict__ src, const float* __restrict__ tgt,
    const u16* __restrict__ Wb2, const float* __restrict__ bias,
    float* __restrict__ out)
{
  __shared__ __align__(16) char As[2][16384];   // 128 rows x 64 bf16, dbuf

  const int tid  = threadIdx.x;
  const int lane = tid & 63;
  const int wid  = tid >> 6;
  const int bn   = blockIdx.x & 7;   // 8 N-tiles (round-robin: 1 bn per XCD)
  const int bm   = blockIdx.x >> 3;  // 512 M-tiles
  const int bt0  = bm * 2;           // two (b,t) rows per M-tile (U=64)
  const int bb   = bt0 >> 7;         // batch
  const int sr0  = tid >> 3;         // staging row 0..31
  const int sc8  = tid & 7;          // staging 16B chunk 0..7
  const int wm   = (wid >> 1) * 64;
  const int wn   = (wid & 1) * 64;

  const float* srcp0 = src + (size_t)bt0 * D_ + sc8 * 8;
  const float* srcp1 = srcp0 + D_;
  const float* tgtp0 = tgt + ((size_t)bb * U_ + sr0) * D_ + sc8 * 8;
  const float* tgtp1 = tgtp0 + (size_t)32 * D_;

  // accumulators, bias-initialized (C/D frag: 4 regs = 4 rows, same col)
  f32x4 acc[4][4];
  #pragma unroll
  for (int ni = 0; ni < 4; ++ni) {
    const float bv = bias[bn * 128 + wn + ni * 16 + (lane & 15)];
    #pragma unroll
    for (int mi = 0; mi < 4; ++mi) acc[mi][ni] = f32x4{bv, bv, bv, bv};
  }

  // B fragment bases: vg = bn*8 + wn/16 + ni; frag kc at +kc*512 u16
  const u16* bfr[4];
  #pragma unroll
  for (int ni = 0; ni < 4; ++ni) {
    const int vg = bn * 8 + (wn >> 4) + ni;
    bfr[ni] = Wb2 + ((size_t)vg * 16 * 64 + lane) * 8;
  }

  float4 pS0a, pS0b, pS1a, pS1b, pT0a, pT0b, pT1a, pT1b;  // A prefetch regs
  bf16x8 bg[4][2];                                        // B frags (regs)

  auto loadA = [&](int kt) {
    const int k0 = kt * 64;
    pS0a = *(const float4*)(srcp0 + k0); pS0b = *(const float4*)(srcp0 + k0 + 4);
    pS1a = *(const float4*)(srcp1 + k0); pS1b = *(const float4*)(srcp1 + k0 + 4);
    pT0a = *(const float4*)(tgtp0 + k0); pT0b = *(const float4*)(tgtp0 + k0 + 4);
    pT1a = *(const float4*)(tgtp1 + k0); pT1b = *(const float4*)(tgtp1 + k0 + 4);
  };

  auto loadBg = [&](int kt) {   // 8 coalesced dwordx4, global->reg
    #pragma unroll
    for (int ni = 0; ni < 4; ++ni)
      #pragma unroll
      for (int s = 0; s < 2; ++s)
        bg[ni][s] = *(const bf16x8*)(bfr[ni] + (size_t)(kt * 2 + s) * 512);
  };

  auto expandA = [&](int nb) {  // relu(src+tgt)->bf16, swizzled ds_write x4
    #pragma unroll
    for (int i = 0; i < 2; ++i) {
      const float4 sa = i ? pS1a : pS0a;
      const float4 sb = i ? pS1b : pS0b;
      #pragma unroll
      for (int j = 0; j < 2; ++j) {
        const float4 ta = j ? pT1a : pT0a;
        const float4 tb = j ? pT1b : pT0b;
        const int r = i * 64 + j * 32 + sr0;
        union { __bf16 h[8]; i32x4 x; } pk;
        pk.h[0] = (__bf16)fmaxf(sa.x + ta.x, 0.f);
        pk.h[1] = (__bf16)fmaxf(sa.y + ta.y, 0.f);
        pk.h[2] = (__bf16)fmaxf(sa.z + ta.z, 0.f);
        pk.h[3] = (__bf16)fmaxf(sa.w + ta.w, 0.f);
        pk.h[4] = (__bf16)fmaxf(sb.x + tb.x, 0.f);
        pk.h[5] = (__bf16)fmaxf(sb.y + tb.y, 0.f);
        pk.h[6] = (__bf16)fmaxf(sb.z + tb.z, 0.f);
        pk.h[7] = (__bf16)fmaxf(sb.w + tb.w, 0.f);
        *(i32x4*)(As[nb] + r * 128 + ((sc8 ^ (r & 7)) << 4)) = pk.x;
      }
    }
  };

  auto compute = [&](int cb) {
    #pragma unroll
    for (int s = 0; s < 2; ++s) {
      const int kc = s * 4 + (lane >> 4);
      bf16x8 af[4];
      #pragma unroll
      for (int mi = 0; mi < 4; ++mi) {
        const int r = wm + mi * 16 + (lane & 15);
        af[mi] = *(const bf16x8*)(As[cb] + r * 128 + ((kc ^ (r & 7)) << 4));
      }
      #pragma unroll
      for (int mi = 0; mi < 4; ++mi)
        #pragma unroll
        for (int ni = 0; ni < 4; ++ni)
          acc[mi][ni] = __builtin_amdgcn_mfma_f32_16x16x32_bf16(
              af[mi], bg[ni][s], acc[mi][ni], 0, 0, 0);
    }
  };

  // ---- prologue: tile 0 into buf 0 ----
  loadA(0);
  expandA(0);                      // waits its f32 loads
  loadBg(0);                       // in flight; compute waits as needed
  asm volatile("s_waitcnt lgkmcnt(0)" ::: "memory");
  __builtin_amdgcn_sched_barrier(0);
  __builtin_amdgcn_s_barrier();
  __builtin_amdgcn_sched_barrier(0);

  // ---- K-loop: ONE barrier per tile ----
  // Race-free: expand(t+1) targets the other buffer; bar(t) separates it
  // from all waves' compute(t) on that buffer.
  for (int kt = 0; kt < 8; ++kt) {
    if (kt < 7) loadA(kt + 1);                   // ages under compute
    __builtin_amdgcn_sched_barrier(0);
    compute(kt & 1);                             // af(LDS buf) x bg(regs)
    if (kt < 7) {
      __builtin_amdgcn_sched_barrier(0);
      loadBg(kt + 1);                            // bg regs free after compute
      expandA((kt + 1) & 1);                     // other buffer; overlaps
                                                 // other waves' MFMA
      asm volatile("s_waitcnt lgkmcnt(0)" ::: "memory");  // ds_writes visible
      __builtin_amdgcn_sched_barrier(0);
      __builtin_amdgcn_s_barrier();              // single barrier per tile
      __builtin_amdgcn_sched_barrier(0);
    }
  }

  // ---- epilogue: pure stores; C/D layout col=lane&15, row=(lane>>4)*4+reg
  const int col = lane & 15;
  const int r4  = (lane >> 4) * 4;
  #pragma unroll
  for (int mi = 0; mi < 4; ++mi) {
    const size_t mrow = (size_t)bm * 128 + wm + mi * 16 + r4;
    float* op0 = out + mrow * V_ + bn * 128 + wn + col;
    #pragma unroll
    for (int ni = 0; ni < 4; ++ni) {
      float* op = op0 + ni * 16;
      const f32x4 v = acc[mi][ni];
      op[0 * V_] = v[0];
      op[1 * V_] = v[1];
      op[2 * V_] = v[2];
      op[3 * V_] = v[3];
    }
  }
}

// ---------------------------------------------------------------------------
// Fallback (ws too small): round-1 fused kernel, f32 W in-loop.
// ---------------------------------------------------------------------------
__global__ __launch_bounds__(256, 2) void joiner_gemm_f32(
    const float* __restrict__ src, const float* __restrict__ tgt,
    const float* __restrict__ Wf, const float* __restrict__ bias,
    float* __restrict__ out)
{
  __shared__ char As[128 * 128];
  __shared__ char Bs[128 * 128];

  const int tid  = threadIdx.x;
  const int lane = tid & 63;
  const int wid  = tid >> 6;
  const int bn   = blockIdx.x & 7;
  const int bm   = blockIdx.x >> 3;
  const int bt0  = bm * 2;
  const int bb   = bt0 >> 7;
  const int sr0  = tid >> 3;
  const int sc8  = tid & 7;
  const int wm   = (wid >> 1) * 64;
  const int wn   = (wid & 1) * 64;

  f32x4 acc[4][4] = {};

  const float* srcp0 = src + (size_t)bt0 * D_ + sc8 * 8;
  const float* srcp1 = srcp0 + D_;
  const float* tgtp0 = tgt + ((size_t)bb * U_ + sr0) * D_ + sc8 * 8;
  const float* tgtp1 = tgtp0 + (size_t)32 * D_;

  for (int kt = 0; kt < 8; ++kt) {
    const int k0 = kt * 64;
    #pragma unroll
    for (int jj = 0; jj < 4; ++jj) {
      const int vr = sr0 + 32 * jj;
      const float* wp = Wf + (size_t)(bn * 128 + vr) * D_ + k0 + sc8 * 8;
      float4 w0 = *(const float4*)wp;
      float4 w1 = *(const float4*)(wp + 4);
      union { __bf16 h[8]; i32x4 x; } pk;
      pk.h[0] = (__bf16)w0.x; pk.h[1] = (__bf16)w0.y;
      pk.h[2] = (__bf16)w0.z; pk.h[3] = (__bf16)w0.w;
      pk.h[4] = (__bf16)w1.x; pk.h[5] = (__bf16)w1.y;
      pk.h[6] = (__bf16)w1.z; pk.h[7] = (__bf16)w1.w;
      *(i32x4*)(Bs + vr * 128 + ((sc8 ^ (vr & 7)) << 4)) = pk.x;
    }
    float4 s0a = *(const float4*)(srcp0 + k0), s0b = *(const float4*)(srcp0 + k0 + 4);
    float4 s1a = *(const float4*)(srcp1 + k0), s1b = *(const float4*)(srcp1 + k0 + 4);
    float4 t0a = *(const float4*)(tgtp0 + k0), t0b = *(const float4*)(tgtp0 + k0 + 4);
    float4 t1a = *(const float4*)(tgtp1 + k0), t1b = *(const float4*)(tgtp1 + k0 + 4);
    #pragma unroll
    for (int i = 0; i < 2; ++i) {
      const float4 sa = i ? s1a : s0a;
      const float4 sb = i ? s1b : s0b;
      #pragma unroll
      for (int jj = 0; jj < 2; ++jj) {
        const float4 ta = jj ? t1a : t0a;
        const float4 tb = jj ? t1b : t0b;
        const int r = i * 64 + jj * 32 + sr0;
        union { __bf16 h[8]; i32x4 x; } pk;
        pk.h[0] = (__bf16)fmaxf(sa.x + ta.x, 0.f);
        pk.h[1] = (__bf16)fmaxf(sa.y + ta.y, 0.f);
        pk.h[2] = (__bf16)fmaxf(sa.z + ta.z, 0.f);
        pk.h[3] = (__bf16)fmaxf(sa.w + ta.w, 0.f);
        pk.h[4] = (__bf16)fmaxf(sb.x + tb.x, 0.f);
        pk.h[5] = (__bf16)fmaxf(sb.y + tb.y, 0.f);
        pk.h[6] = (__bf16)fmaxf(sb.z + tb.z, 0.f);
        pk.h[7] = (__bf16)fmaxf(sb.w + tb.w, 0.f);
        *(i32x4*)(As + r * 128 + ((sc8 ^ (r & 7)) << 4)) = pk.x;
      }
    }
    __syncthreads();
    #pragma unroll
    for (int s = 0; s < 2; ++s) {
      const int kc = s * 4 + (lane >> 4);
      bf16x8 af[4], bg[4];
      #pragma unroll
      for (int mi = 0; mi < 4; ++mi) {
        const int r = wm + mi * 16 + (lane & 15);
        af[mi] = *(const bf16x8*)(As + r * 128 + ((kc ^ (r & 7)) << 4));
      }
      #pragma unroll
      for (int ni = 0; ni < 4; ++ni) {
        const int n = wn + ni * 16 + (lane & 15);
        bg[ni] = *(const bf16x8*)(Bs + n * 128 + ((kc ^ (n & 7)) << 4));
      }
      #pragma unroll
      for (int mi = 0; mi < 4; ++mi)
        #pragma unroll
        for (int ni = 0; ni < 4; ++ni)
          acc[mi][ni] = __builtin_amdgcn_mfma_f32_16x16x32_bf16(
              af[mi], bg[ni], acc[mi][ni], 0, 0, 0);
    }
    __syncthreads();
  }

  const int col = lane & 15;
  const int r4  = (lane >> 4) * 4;
  float bv[4];
  #pragma unroll
  for (int ni = 0; ni < 4; ++ni) bv[ni] = bias[bn * 128 + wn + ni * 16 + col];
  #pragma unroll
  for (int mi = 0; mi < 4; ++mi) {
    const size_t mrow = (size_t)bm * 128 + wm + mi * 16 + r4;
    float* op0 = out + mrow * V_ + bn * 128 + wn + col;
    #pragma unroll
    for (int ni = 0; ni < 4; ++ni) {
      float* op = op0 + ni * 16;
      const f32x4 v = acc[mi][ni];
      op[0 * V_] = v[0] + bv[ni];
      op[1 * V_] = v[1] + bv[ni];
      op[2 * V_] = v[2] + bv[ni];
      op[3 * V_] = v[3] + bv[ni];
    }
  }
}

extern "C" void kernel_launch(void* const* d_in, const int* in_sizes, int n_in,
                              void* d_out, int out_size, void* d_ws, size_t ws_size,
                              hipStream_t stream) {
  const float* src  = (const float*)d_in[0];
  const int*   sl   = (const int*)d_in[1];
  const float* tgt  = (const float*)d_in[2];
  const int*   tl   = (const int*)d_in[3];
  const float* W    = (const float*)d_in[4];
  const float* bias = (const float*)d_in[5];
  float* out  = (float*)d_out;
  float* tail = out + (size_t)M_ * V_;

  if (ws_size >= (size_t)V_ * D_ * sizeof(u16)) {
    u16* Wb2 = (u16*)d_ws;
    prep_w<<<256, 256, 0, stream>>>(W, sl, tl, Wb2, tail);
    joiner_gemm<<<(M_ / 128) * (V_ / 128), 256, 0, stream>>>(
        src, tgt, Wb2, bias, out);
  } else {
    tail_k<<<1, 64, 0, stream>>>(sl, tl, tail);
    joiner_gemm_f32<<<(M_ / 128) * (V_ / 128), 256, 0, stream>>>(
        src, tgt, W, bias, out);
  }
}